// Round 17
// baseline (105.542 us; speedup 1.0000x reference)
//
#include <hip/hip_runtime.h>

// Koopman bilinear rollout: preds[b,t,d] = (z0 @ Kd^{t+1})[b,d], D=B=256, T=512.
// r17 = r16 with the NT-store compile fix (native ext_vector f32x4, not HIP
// float4 class). Structure = r15 (proven 96.7us) + polish: NT stores for
// fill's C, L1 drops dead Zf stores, comb reads K direct.
//   M_j = I + sum_{m<=8} g_m^(j) cs^m K^m ; comb emits 32 bf16-T M-tables,
//   W1..W5 = Kd^{32..160} f32, bf16(z0). Scan: L0 Z1..5 + W10 ; L1 Z6..15.
// Chain: p1,g2a,g2b,g3,comb,L0,L1,fill (depth 7: g2a/g2b independent).
// DEAD ENDS (do not retry): persistent kernel + grid barrier (r5 392us,
// r7 289us); 256x256 fill tile (r11, -5us); fill j-major ~neutral (r13);
// input-staging dbuf (r4 neutral). Budget: ~3.5us/launch-gap, fill ~29us.

#define DD 256
#define TT 512
#define MATF (DD * DD)
#define LDT ((size_t)TT * (size_t)DD)

typedef __attribute__((ext_vector_type(8))) short bf16x8;
typedef __attribute__((ext_vector_type(4))) float f32x4;

#define GLD16(g, l)                                                  \
    __builtin_amdgcn_global_load_lds(                                \
        (const __attribute__((address_space(1))) void*)(g),          \
        (__attribute__((address_space(3))) void*)(l), 16, 0, 0)

static __device__ __forceinline__ unsigned short f2bf(float f) {
    unsigned int u = __float_as_uint(f);
    u += 0x7fffu + ((u >> 16) & 1u);
    return (unsigned short)(u >> 16);
}
static __device__ __forceinline__ unsigned pack2bf(float a, float b) {
    return (unsigned)f2bf(a) | ((unsigned)f2bf(b) << 16);
}

// ---- 32x32-tile f32 GEMM core: 256 threads, K=256, K_BLK=64, reg prefetch ----
__device__ __forceinline__ void g32_core(const float* __restrict__ Ab, int lda,
                                         const float* __restrict__ Bb, int ldb,
                                         int rowBase, int colBase, float acc[2][2]) {
    __shared__ __align__(16) float As[64 * 38];
    __shared__ __align__(16) float Bs[64 * 40];
    const int tid = threadIdx.x;
    const int tx = tid & 15, ty = tid >> 4;
    const int am = tid >> 4;
    const int ak = (tid & 15) << 2;
    const int bk = tid >> 3;
    const int bn = (tid & 7) << 2;

    acc[0][0] = acc[0][1] = acc[1][0] = acc[1][1] = 0.f;

    float4 pa0 = *(const float4*)(Ab + (size_t)(rowBase + am) * lda + ak);
    float4 pa1 = *(const float4*)(Ab + (size_t)(rowBase + am + 16) * lda + ak);
    float4 pb0 = *(const float4*)(Bb + (size_t)bk * ldb + colBase + bn);
    float4 pb1 = *(const float4*)(Bb + (size_t)(bk + 32) * ldb + colBase + bn);

    for (int k0 = 0; k0 < DD; k0 += 64) {
        As[(ak + 0) * 38 + am] = pa0.x;
        As[(ak + 1) * 38 + am] = pa0.y;
        As[(ak + 2) * 38 + am] = pa0.z;
        As[(ak + 3) * 38 + am] = pa0.w;
        As[(ak + 0) * 38 + am + 16] = pa1.x;
        As[(ak + 1) * 38 + am + 16] = pa1.y;
        As[(ak + 2) * 38 + am + 16] = pa1.z;
        As[(ak + 3) * 38 + am + 16] = pa1.w;
        *(float4*)(&Bs[bk * 40 + bn]) = pb0;
        *(float4*)(&Bs[(bk + 32) * 40 + bn]) = pb1;
        __syncthreads();
        if (k0 + 64 < DD) {
            pa0 = *(const float4*)(Ab + (size_t)(rowBase + am) * lda + k0 + 64 + ak);
            pa1 = *(const float4*)(Ab + (size_t)(rowBase + am + 16) * lda + k0 + 64 + ak);
            pb0 = *(const float4*)(Bb + (size_t)(bk + k0 + 64) * ldb + colBase + bn);
            pb1 = *(const float4*)(Bb + (size_t)(bk + 32 + k0 + 64) * ldb + colBase + bn);
        }
#pragma unroll
        for (int kk = 0; kk < 64; ++kk) {
            float2 a2 = *(const float2*)(&As[kk * 38 + (ty << 1)]);
            float2 b2 = *(const float2*)(&Bs[kk * 40 + (tx << 1)]);
            acc[0][0] = fmaf(a2.x, b2.x, acc[0][0]);
            acc[0][1] = fmaf(a2.x, b2.y, acc[0][1]);
            acc[1][0] = fmaf(a2.y, b2.x, acc[1][0]);
            acc[1][1] = fmaf(a2.y, b2.y, acc[1][1]);
        }
        __syncthreads();
    }
}

// p1: Pw[0] = K@K  (= K^2)
__global__ void __launch_bounds__(256)
p1_kernel(const float* __restrict__ K, float* __restrict__ Pw) {
    float acc[2][2];
    const int rowBase = blockIdx.y << 5, colBase = blockIdx.x << 5;
    g32_core(K, DD, K, DD, rowBase, colBase, acc);
    const int r0 = rowBase + ((threadIdx.x >> 4) << 1);
    const int c0 = colBase + ((threadIdx.x & 15) << 1);
#pragma unroll
    for (int i = 0; i < 2; ++i) {
        int r = r0 + i;
        *(float2*)(Pw + (size_t)r * DD + c0) = (float2){acc[i][0], acc[i][1]};
    }
}

// generic batched 256^3 f32 GEMM
__global__ void __launch_bounds__(256)
gpow_kernel(const float* __restrict__ A, const float* __restrict__ B,
            float* __restrict__ C, long long sA, long long sB, long long sC) {
    float acc[2][2];
    const int rowBase = blockIdx.y << 5, colBase = blockIdx.x << 5;
    g32_core(A + blockIdx.z * sA, DD, B + blockIdx.z * sB, DD, rowBase, colBase, acc);
    float* Cb = C + blockIdx.z * sC;
    const int r0 = rowBase + ((threadIdx.x >> 4) << 1);
    const int c0 = colBase + ((threadIdx.x & 15) << 1);
#pragma unroll
    for (int i = 0; i < 2; ++i) {
        int r = r0 + i;
        *(float2*)(Cb + (size_t)r * DD + c0) = (float2){acc[i][0], acc[i][1]};
    }
}

// stage 3 (batch 4): K^5=K^2@K^3, K^6=K^3@K^3, K^7=K^3@K^4, K^8=K^4@K^4
// Pw slots: 0=K^2, 1=K^3, 2=K^4, 3=K^5, 4=K^6, 5=K^7, 6=K^8
__global__ void __launch_bounds__(256)
gpow4_kernel(float* __restrict__ Pw) {
    static const int sa[4] = {0, 1, 1, 2};
    static const int sb[4] = {1, 1, 2, 2};
    static const int sc[4] = {3, 4, 5, 6};
    const int z = blockIdx.z;
    float acc[2][2];
    const int rowBase = blockIdx.y << 5, colBase = blockIdx.x << 5;
    g32_core(Pw + (size_t)sa[z] * MATF, DD, Pw + (size_t)sb[z] * MATF, DD,
             rowBase, colBase, acc);
    float* Cb = Pw + (size_t)sc[z] * MATF;
    const int r0 = rowBase + ((threadIdx.x >> 4) << 1);
    const int c0 = colBase + ((threadIdx.x & 15) << 1);
#pragma unroll
    for (int i = 0; i < 2; ++i) {
        int r = r0 + i;
        *(float2*)(Cb + (size_t)r * DD + c0) = (float2){acc[i][0], acc[i][1]};
    }
}

// comb: M_j = I + sum_{m=1..8} g_m^(j) cs^m K^m (j=1..32) -> bf16 MTb[j][c][k]
// + f32 W1..W5 = Kd^{32,64,96,128,160} + Zb0 = bf16(z0).
// K^1 read from Kmat directly; K^2..K^8 from Pw[0..6].
__global__ void __launch_bounds__(256)
comb_kernel(const float* __restrict__ Kmat, const float* __restrict__ Pw,
            const float* __restrict__ log_dt, const float* __restrict__ z0,
            unsigned short* __restrict__ MTb, float* __restrict__ W1,
            float* __restrict__ W2, float* __restrict__ W3,
            float* __restrict__ W4, float* __restrict__ W5,
            unsigned short* __restrict__ Zb0) {
    __shared__ float tle[8][32][33];
    __shared__ float gtab[36][8];
    const int tid = threadIdx.x;
    const int k0 = blockIdx.y << 5, c0 = blockIdx.x << 5;
    const float csf = 0.5f * expf(log_dt[0]);

    // fold prep: bf16(z0), 4 elems/thread
    {
        int b = ((blockIdx.y * 8 + blockIdx.x) * 256 + tid) * 4;
        uint2 w;
        w.x = pack2bf(z0[b], z0[b + 1]);
        w.y = pack2bf(z0[b + 2], z0[b + 3]);
        *(uint2*)(Zb0 + b) = w;
    }

    // coefficient rows: 0..31 -> j=1..32 ; 32..35 -> j=64,96,128,160
    if (tid < 36) {
        int j = (tid < 32) ? (tid + 1) : (32 * (tid - 30));
        double b[9], cq[9];
        b[0] = 1.0;
        cq[0] = 1.0;
#pragma unroll
        for (int p = 1; p <= 8; ++p) {
            b[p] = b[p - 1] * (double)(j - p + 1) / (double)p;   // C(j,p)
            cq[p] = cq[p - 1] * (double)(j + p - 1) / (double)p; // C(j+p-1,p)
        }
        double csm = (double)csf;
#pragma unroll
        for (int m = 1; m <= 8; ++m) {
            double s = 0.0;
#pragma unroll
            for (int p = 0; p <= 8; ++p)
                if (p <= m) s += b[p] * cq[m - p];
            gtab[tid][m - 1] = (float)(s * csm);
            csm *= (double)csf;
        }
    }

    const int ltx = tid & 31, lty = tid >> 5;
#pragma unroll
    for (int m = 0; m < 8; ++m) {
        const float* src = (m == 0) ? Kmat : Pw + (size_t)(m - 1) * MATF;
#pragma unroll
        for (int it = 0; it < 4; ++it) {
            int k = lty + (it << 3);
            tle[m][ltx][k] = src[(size_t)(k0 + k) * DD + c0 + ltx];
        }
    }
    __syncthreads();

    const int c = tid >> 3;
    const int kb = (tid & 7) << 2;
    float em[8][4];
#pragma unroll
    for (int m = 0; m < 8; ++m)
#pragma unroll
        for (int u = 0; u < 4; ++u) em[m][u] = tle[m][c][kb + u];

    float diag[4];
#pragma unroll
    for (int u = 0; u < 4; ++u)
        diag[u] = ((k0 + kb + u) == (c0 + c)) ? 1.f : 0.f;

    float w32[4];
    for (int j = 1; j <= 32; ++j) {
        float val[4] = {diag[0], diag[1], diag[2], diag[3]};
        const float* gj = gtab[j - 1];
#pragma unroll
        for (int m = 0; m < 8; ++m)
#pragma unroll
            for (int u = 0; u < 4; ++u) val[u] = fmaf(gj[m], em[m][u], val[u]);
        uint2 w;
        w.x = pack2bf(val[0], val[1]);
        w.y = pack2bf(val[2], val[3]);
        *(uint2*)(MTb + (size_t)(j - 1) * MATF + (size_t)(c0 + c) * DD + k0 + kb) = w;
        if (j == 32) {
            w32[0] = val[0]; w32[1] = val[1]; w32[2] = val[2]; w32[3] = val[3];
        }
    }
    float wv[4][4];
#pragma unroll
    for (int q = 0; q < 4; ++q)
#pragma unroll
        for (int u = 0; u < 4; ++u) wv[q][u] = diag[u];
#pragma unroll
    for (int m = 0; m < 8; ++m)
#pragma unroll
        for (int q = 0; q < 4; ++q)
#pragma unroll
            for (int u = 0; u < 4; ++u)
                wv[q][u] = fmaf(gtab[32 + q][m], em[m][u], wv[q][u]);

    // five LDS-transpose passes -> coalesced f32 stores in [k][c] layout
    float* tw = &tle[0][0][0];
    const int wk = tid >> 3, wc = (tid & 7) << 2;
    float* Wd[5] = {W1, W2, W3, W4, W5};
    float* Ws[5] = {w32, wv[0], wv[1], wv[2], wv[3]};
#pragma unroll
    for (int p = 0; p < 5; ++p) {
        __syncthreads();
#pragma unroll
        for (int u = 0; u < 4; ++u) tw[(kb + u) * 33 + c] = Ws[p][u];
        __syncthreads();
        float4 v = {tw[wk * 33 + wc], tw[wk * 33 + wc + 1],
                    tw[wk * 33 + wc + 2], tw[wk * 33 + wc + 3]};
        *(float4*)(Wd[p] + (size_t)(k0 + wk) * DD + c0 + wc) = v;
    }
}

// 2-level checkpoint scan. Wp = {W1,W2,W3,W4,W5,W10}.
// L0 (6): Z1..Z5 = z0@W1..5 ; W10 = W5@W5.
// L1 (10): Z6..Z10 = Z1..5@W5 ; Z11..Z15 = Z1..5@W10 (Zb-only: Zf dead at L1).
__global__ void __launch_bounds__(256)
scan2_kernel(const float* __restrict__ z0, float* __restrict__ Zf,
             const float* __restrict__ W1, const float* __restrict__ W2,
             const float* __restrict__ W3, const float* __restrict__ W4,
             const float* __restrict__ W5, float* __restrict__ Wtab,
             unsigned short* __restrict__ Zb, int level) {
    static const signed char JA[2][10] = {
        {0, 0, 0, 0, 0, 20, 0, 0, 0, 0},
        {1, 2, 3, 4, 5, 1, 2, 3, 4, 5}};
    static const signed char JB[2][10] = {
        {0, 1, 2, 3, 4, 4, 0, 0, 0, 0},
        {4, 4, 4, 4, 4, 5, 5, 5, 5, 5}};
    static const signed char JD[2][10] = {
        {1, 2, 3, 4, 5, 19, 0, 0, 0, 0},
        {6, 7, 8, 9, 10, 11, 12, 13, 14, 15}};
    const float* Wp[6] = {W1, W2, W3, W4, W5, Wtab};
    const int jz = blockIdx.z;
    const int a = JA[level][jz], b = JB[level][jz], d = JD[level][jz];

    const float* Asrc;
    if (a == 0) Asrc = z0;
    else if (a < 16) Asrc = Zf + (size_t)a * MATF;
    else Asrc = Wp[a - 16];

    float acc[2][2];
    const int rowBase = blockIdx.y << 5, colBase = blockIdx.x << 5;
    g32_core(Asrc, DD, Wp[b], DD, rowBase, colBase, acc);

    const int r0 = rowBase + ((threadIdx.x >> 4) << 1);
    const int c0 = colBase + ((threadIdx.x & 15) << 1);
    if (d < 16) {
        unsigned short* Zo = Zb + (size_t)d * MATF;
#pragma unroll
        for (int ii = 0; ii < 2; ++ii) {
            int r = r0 + ii;
            float2 v = {acc[ii][0], acc[ii][1]};
            if (level == 0)  // L1's Zf outputs are dead (only Zb feeds fill)
                *(float2*)(Zf + (size_t)d * MATF + (size_t)r * DD + c0) = v;
            *(unsigned*)(Zo + (size_t)r * DD + c0) = pack2bf(v.x, v.y);
        }
    } else {
        float* Cb = Wtab;
#pragma unroll
        for (int ii = 0; ii < 2; ++ii) {
            int r = r0 + ii;
            *(float2*)(Cb + (size_t)r * DD + c0) = (float2){acc[ii][0], acc[ii][1]};
        }
    }
}

// Batched bf16 MFMA fill (proven r8/r10/r13), all 512 timesteps, j-major.
// NT stores for C (native ext_vector f32x4 -- HIP float4 class rejected by
// __builtin_nontemporal_store, r16 compile lesson).
__global__ void __launch_bounds__(256)
fill_kernel(const unsigned short* __restrict__ Zb,
            const unsigned short* __restrict__ MTb,
            float* __restrict__ out) {
    __shared__ __align__(16) char pool[32768];
    const int zz = blockIdx.z;
    const int i = zz & 15;
    const int j = (zz >> 4) + 1;
    const int t = i * 32 + j - 1;
    const unsigned short* Zt = Zb + (size_t)i * MATF;
    const unsigned short* MT = MTb + (size_t)(j - 1) * MATF;

    const int tid = threadIdx.x;
    const int lane = tid & 63, wid = tid >> 6;
    const int rowBase = blockIdx.y * 128, colBase = blockIdx.x * 128;
    const int wr = (wid >> 1) * 64, wc = (wid & 1) * 64;

    int rowq[4], skq[4], ldsb[4];
#pragma unroll
    for (int q = 0; q < 4; ++q) {
        int c = q * 256 + wid * 64 + lane;
        int row = c >> 3;
        rowq[q] = row;
        skq[q] = ((c ^ (row & 7)) & 7) << 3;
        ldsb[q] = (q * 256 + wid * 64) << 4;
    }

    f32x4 acc[4][4];
#pragma unroll
    for (int a = 0; a < 4; ++a)
#pragma unroll
        for (int b = 0; b < 4; ++b) acc[a][b] = (f32x4){0.f, 0.f, 0.f, 0.f};

    auto stage = [&](int k0) {
#pragma unroll
        for (int q = 0; q < 4; ++q) {
            GLD16(Zt + (size_t)(rowBase + rowq[q]) * DD + k0 + skq[q], pool + ldsb[q]);
            GLD16(MT + (size_t)(colBase + rowq[q]) * DD + k0 + skq[q],
                  pool + 16384 + ldsb[q]);
        }
    };

    stage(0);
    for (int r = 0; r < 4; ++r) {
        __syncthreads();
        const char* asb = pool;
        const char* bsb = pool + 16384;
#pragma unroll
        for (int ks = 0; ks < 2; ++ks) {
            bf16x8 af[4], bg[4];
            const int kk = ks * 32 + (lane >> 4) * 8;
#pragma unroll
            for (int f = 0; f < 4; ++f) {
                int rr = wr + f * 16 + (lane & 15);
                af[f] = *(const bf16x8*)(asb + ((rr * 128 + kk * 2) ^ ((rr & 7) << 4)));
                int cc = wc + f * 16 + (lane & 15);
                bg[f] = *(const bf16x8*)(bsb + ((cc * 128 + kk * 2) ^ ((cc & 7) << 4)));
            }
#pragma unroll
            for (int fr = 0; fr < 4; ++fr)
#pragma unroll
                for (int fc = 0; fc < 4; ++fc)
                    acc[fr][fc] = __builtin_amdgcn_mfma_f32_16x16x32_bf16(
                        af[fr], bg[fc], acc[fr][fc], 0, 0, 0);
        }
        __syncthreads();
        if (r < 3) stage((r + 1) * 64);
    }

    float* Cs = (float*)pool;
    float* C = out + (size_t)t * DD;
#pragma unroll
    for (int hp = 0; hp < 2; ++hp) {
        __syncthreads();
        if (wr == hp * 64) {
#pragma unroll
            for (int fr = 0; fr < 4; ++fr) {
#pragma unroll
                for (int fc = 0; fc < 4; ++fc) {
                    int ccol = wc + fc * 16 + (lane & 15);
#pragma unroll
                    for (int ii = 0; ii < 4; ++ii) {
                        int lr = fr * 16 + ((lane >> 4) << 2) + ii;
                        int csw = ccol ^ (((lr >> 2) & 1) << 4);
                        Cs[lr * 128 + csw] = acc[fr][fc][ii];
                    }
                }
            }
        }
        __syncthreads();
#pragma unroll
        for (int it = 0; it < 8; ++it) {
            int chunk = it * 256 + tid;
            int row = chunk >> 5;
            int c4 = (chunk & 31) << 2;
            int csw = c4 ^ (((row >> 2) & 1) << 4);
            f32x4 v = *(const f32x4*)(Cs + row * 128 + csw);
            __builtin_nontemporal_store(
                v, (f32x4*)(C + (size_t)(rowBase + hp * 64 + row) * LDT +
                            colBase + c4));
        }
    }
}

// ---------------- fallback (tiny ws): proven g32 chain ----------------------
__global__ void prep_kernel(const float* __restrict__ K,
                            const float* __restrict__ log_dt,
                            float* __restrict__ A) {
    int idx = blockIdx.x * blockDim.x + threadIdx.x;
    A[idx] = 0.5f * expf(log_dt[0]) * K[idx];
}

template <int EPI>
__global__ void __launch_bounds__(256)
g32_kernel(const float* A, const float* B, float* C, const float* E, float* C2,
           int lda, int ldb, int ldc, long long sA, long long sB, long long sC) {
    float acc[2][2];
    const int rowBase = blockIdx.y << 5, colBase = blockIdx.x << 5;
    g32_core(A + blockIdx.z * sA, lda, B + blockIdx.z * sB, ldb, rowBase, colBase, acc);
    float* Cb = C + blockIdx.z * sC;
    const int r0 = rowBase + ((threadIdx.x >> 4) << 1);
    const int c0 = colBase + ((threadIdx.x & 15) << 1);
#pragma unroll
    for (int i = 0; i < 2; ++i) {
        int r = r0 + i;
        float2 v;
        if (EPI == 2) {
            float e0 = E[(size_t)r * DD + c0], e1 = E[(size_t)r * DD + c0 + 1];
            v.x = acc[i][0] + 2.f * e0 + (r == c0 ? 1.f : 0.f);
            v.y = acc[i][1] + 2.f * e1 + (r == c0 + 1 ? 1.f : 0.f);
        } else {
            v.x = acc[i][0];
            v.y = acc[i][1];
        }
        *(float2*)(Cb + (size_t)r * ldc + c0) = v;
        if (EPI == 1) {
            float e0 = E[(size_t)r * DD + c0], e1 = E[(size_t)r * DD + c0 + 1];
            float2 w;
            w.x = 2.f * acc[i][0] + 2.f * e0 + (r == c0 ? 2.f : 0.f);
            w.y = 2.f * acc[i][1] + 2.f * e1 + (r == c0 + 1 ? 2.f : 0.f);
            *(float2*)(C2 + (size_t)r * DD + c0) = w;
        }
    }
}

// ---------------- launch ----------------------------------------------------
extern "C" void kernel_launch(void* const* d_in, const int* in_sizes, int n_in,
                              void* d_out, int out_size, void* d_ws, size_t ws_size,
                              hipStream_t stream) {
    const float* z0 = (const float*)d_in[0];
    const float* Kmat = (const float*)d_in[1];
    const float* log_dt = (const float*)d_in[2];
    float* out = (float*)d_out;

    dim3 blk(256);

    // ws: Pw[7] (K^2..K^8) | W1..W5 | Wtab[1] (W10) | Zf[16] f32
    //     | MTb[32] | Zb[16] bf16
    float* Pw = (float*)d_ws;
    float* W1 = Pw + (size_t)7 * MATF;
    float* W2 = W1 + MATF;
    float* W3 = W2 + MATF;
    float* W4 = W3 + MATF;
    float* W5 = W4 + MATF;
    float* Wtab = W5 + MATF;
    float* Zf = Wtab + MATF;
    unsigned short* MTb = (unsigned short*)(Zf + (size_t)16 * MATF);
    unsigned short* Zb = MTb + (size_t)32 * MATF;
    const size_t need = (size_t)29 * MATF * 4 + (size_t)48 * MATF * 2;

    if (ws_size >= need) {
        dim3 g(8, 8, 1);
        // K-powers: K^2 ; K^3 = K@K^2 ; K^4 = K^2@K^2 ; {K^5..K^8}
        p1_kernel<<<g, blk, 0, stream>>>(Kmat, Pw);
        gpow_kernel<<<g, blk, 0, stream>>>(Kmat, Pw, Pw + MATF, 0, 0, 0);
        gpow_kernel<<<g, blk, 0, stream>>>(Pw, Pw, Pw + 2 * (size_t)MATF, 0, 0, 0);
        gpow4_kernel<<<dim3(8, 8, 4), blk, 0, stream>>>(Pw);

        // All 32 M-tables (bf16-T) + W1..W5 f32 + bf16(z0), one launch
        comb_kernel<<<g, blk, 0, stream>>>(Kmat, Pw, log_dt, z0, MTb, W1, W2,
                                           W3, W4, W5, Zb);

        // checkpoint scan: 2 batched levels
        scan2_kernel<<<dim3(8, 8, 6), blk, 0, stream>>>(z0, Zf, W1, W2, W3, W4,
                                                        W5, Wtab, Zb, 0);
        scan2_kernel<<<dim3(8, 8, 10), blk, 0, stream>>>(z0, Zf, W1, W2, W3, W4,
                                                         W5, Wtab, Zb, 1);

        // ALL 512 timesteps, j-major order, NT stores
        fill_kernel<<<dim3(2, 2, 512), blk, 0, stream>>>(Zb, MTb, out);
        return;
    }

    // Minimal fallback (tiny ws): Kd then 512 chained GEMMs (f32, proven core).
    float* A = (float*)d_ws;
    float* A2f = A + MATF;
    float* Bopf = A2f + MATF;
    float* Kd = Bopf + MATF;
    prep_kernel<<<MATF / 256, blk, 0, stream>>>(Kmat, log_dt, A);
    dim3 g(8, 8, 1);
    g32_kernel<1><<<g, blk, 0, stream>>>(A, A, A2f, A, Bopf, DD, DD, DD, 0, 0, 0);
    g32_kernel<2><<<g, blk, 0, stream>>>(A2f, Bopf, Kd, A, (float*)0, DD, DD, DD, 0, 0, 0);
    for (int t = 0; t < TT; ++t) {
        const float* Ain = (t == 0) ? z0 : out + (size_t)(t - 1) * DD;
        int lda = (t == 0) ? DD : (int)LDT;
        g32_kernel<0><<<g, blk, 0, stream>>>(Ain, Kd, out + (size_t)t * DD,
                                             (const float*)0, (float*)0,
                                             lda, DD, (int)LDT, 0, 0, 0);
    }
}

// Round 18
// 96.929 us; speedup vs baseline: 1.0889x; 1.0889x over previous
//
#include <hip/hip_runtime.h>

// Koopman bilinear rollout: preds[b,t,d] = (z0 @ Kd^{t+1})[b,d], D=B=256, T=512.
// r18 = exact revert to r15 (proven 96.7us). r16/r17's polish REGRESSED
// (+8.8us): NT stores bypass L2 write-coalescing, and un-batching {K^3,K^4}
// added a launch. Keep plain stores + 7-launch chain.
//   M_j = I + sum_{m<=8} g_m^(j) cs^m K^m ; comb emits 32 bf16-T M-tables,
//   W1..W5 = Kd^{32..160} f32 (order-8, W5 trunc ~2e-4 rel), bf16(z0).
//   Scan: L0 Z1..5 + W10=W5@W5 ; L1 Z6..15. Then one batched bf16-MFMA fill.
// Chain: p1, g2(batch2), g3(batch4), comb, L0, L1, fill = 7 launches.
// DEAD ENDS (do not retry): persistent kernel + grid barrier (r5 392us,
// r7 289us); 256x256 fill tile (r11); fill j-major ~neutral (r13);
// input-staging dbuf (r4 neutral); NT C-stores (r17, +4-8us).

#define DD 256
#define TT 512
#define MATF (DD * DD)
#define LDT ((size_t)TT * (size_t)DD)

typedef __attribute__((ext_vector_type(8))) short bf16x8;
typedef __attribute__((ext_vector_type(4))) float f32x4;

#define GLD16(g, l)                                                  \
    __builtin_amdgcn_global_load_lds(                                \
        (const __attribute__((address_space(1))) void*)(g),          \
        (__attribute__((address_space(3))) void*)(l), 16, 0, 0)

static __device__ __forceinline__ unsigned short f2bf(float f) {
    unsigned int u = __float_as_uint(f);
    u += 0x7fffu + ((u >> 16) & 1u);
    return (unsigned short)(u >> 16);
}
static __device__ __forceinline__ unsigned pack2bf(float a, float b) {
    return (unsigned)f2bf(a) | ((unsigned)f2bf(b) << 16);
}

// ---- 32x32-tile f32 GEMM core: 256 threads, K=256, K_BLK=64, reg prefetch ----
__device__ __forceinline__ void g32_core(const float* __restrict__ Ab, int lda,
                                         const float* __restrict__ Bb, int ldb,
                                         int rowBase, int colBase, float acc[2][2]) {
    __shared__ __align__(16) float As[64 * 38];
    __shared__ __align__(16) float Bs[64 * 40];
    const int tid = threadIdx.x;
    const int tx = tid & 15, ty = tid >> 4;
    const int am = tid >> 4;
    const int ak = (tid & 15) << 2;
    const int bk = tid >> 3;
    const int bn = (tid & 7) << 2;

    acc[0][0] = acc[0][1] = acc[1][0] = acc[1][1] = 0.f;

    float4 pa0 = *(const float4*)(Ab + (size_t)(rowBase + am) * lda + ak);
    float4 pa1 = *(const float4*)(Ab + (size_t)(rowBase + am + 16) * lda + ak);
    float4 pb0 = *(const float4*)(Bb + (size_t)bk * ldb + colBase + bn);
    float4 pb1 = *(const float4*)(Bb + (size_t)(bk + 32) * ldb + colBase + bn);

    for (int k0 = 0; k0 < DD; k0 += 64) {
        As[(ak + 0) * 38 + am] = pa0.x;
        As[(ak + 1) * 38 + am] = pa0.y;
        As[(ak + 2) * 38 + am] = pa0.z;
        As[(ak + 3) * 38 + am] = pa0.w;
        As[(ak + 0) * 38 + am + 16] = pa1.x;
        As[(ak + 1) * 38 + am + 16] = pa1.y;
        As[(ak + 2) * 38 + am + 16] = pa1.z;
        As[(ak + 3) * 38 + am + 16] = pa1.w;
        *(float4*)(&Bs[bk * 40 + bn]) = pb0;
        *(float4*)(&Bs[(bk + 32) * 40 + bn]) = pb1;
        __syncthreads();
        if (k0 + 64 < DD) {
            pa0 = *(const float4*)(Ab + (size_t)(rowBase + am) * lda + k0 + 64 + ak);
            pa1 = *(const float4*)(Ab + (size_t)(rowBase + am + 16) * lda + k0 + 64 + ak);
            pb0 = *(const float4*)(Bb + (size_t)(bk + k0 + 64) * ldb + colBase + bn);
            pb1 = *(const float4*)(Bb + (size_t)(bk + 32 + k0 + 64) * ldb + colBase + bn);
        }
#pragma unroll
        for (int kk = 0; kk < 64; ++kk) {
            float2 a2 = *(const float2*)(&As[kk * 38 + (ty << 1)]);
            float2 b2 = *(const float2*)(&Bs[kk * 40 + (tx << 1)]);
            acc[0][0] = fmaf(a2.x, b2.x, acc[0][0]);
            acc[0][1] = fmaf(a2.x, b2.y, acc[0][1]);
            acc[1][0] = fmaf(a2.y, b2.x, acc[1][0]);
            acc[1][1] = fmaf(a2.y, b2.y, acc[1][1]);
        }
        __syncthreads();
    }
}

// p1: Pw[0] = K (copy) ; Pw[1] = K@K
__global__ void __launch_bounds__(256)
p1_kernel(const float* __restrict__ K, float* __restrict__ Pw) {
    {
        int b = ((blockIdx.y * 8 + blockIdx.x) * 256 + threadIdx.x) * 4;
        *(float4*)(Pw + b) = *(const float4*)(K + b);
    }
    float acc[2][2];
    const int rowBase = blockIdx.y << 5, colBase = blockIdx.x << 5;
    g32_core(K, DD, K, DD, rowBase, colBase, acc);
    float* Cb = Pw + MATF;
    const int r0 = rowBase + ((threadIdx.x >> 4) << 1);
    const int c0 = colBase + ((threadIdx.x & 15) << 1);
#pragma unroll
    for (int i = 0; i < 2; ++i) {
        int r = r0 + i;
        *(float2*)(Cb + (size_t)r * DD + c0) = (float2){acc[i][0], acc[i][1]};
    }
}

// stage 2 (batch 2): K^3 = K@K^2, K^4 = K^2@K^2
__global__ void __launch_bounds__(256)
gpow_kernel(const float* __restrict__ A, const float* __restrict__ B,
            float* __restrict__ C, long long sA, long long sB, long long sC) {
    float acc[2][2];
    const int rowBase = blockIdx.y << 5, colBase = blockIdx.x << 5;
    g32_core(A + blockIdx.z * sA, DD, B + blockIdx.z * sB, DD, rowBase, colBase, acc);
    float* Cb = C + blockIdx.z * sC;
    const int r0 = rowBase + ((threadIdx.x >> 4) << 1);
    const int c0 = colBase + ((threadIdx.x & 15) << 1);
#pragma unroll
    for (int i = 0; i < 2; ++i) {
        int r = r0 + i;
        *(float2*)(Cb + (size_t)r * DD + c0) = (float2){acc[i][0], acc[i][1]};
    }
}

// stage 3 (batch 4): K^5=K^2@K^3, K^6=K^3@K^3, K^7=K^3@K^4, K^8=K^4@K^4
// (Pw[m-1] = K^m)
__global__ void __launch_bounds__(256)
gpow4_kernel(float* __restrict__ Pw) {
    static const int sa[4] = {1, 2, 2, 3};
    static const int sb[4] = {2, 2, 3, 3};
    static const int sc[4] = {4, 5, 6, 7};
    const int z = blockIdx.z;
    float acc[2][2];
    const int rowBase = blockIdx.y << 5, colBase = blockIdx.x << 5;
    g32_core(Pw + (size_t)sa[z] * MATF, DD, Pw + (size_t)sb[z] * MATF, DD,
             rowBase, colBase, acc);
    float* Cb = Pw + (size_t)sc[z] * MATF;
    const int r0 = rowBase + ((threadIdx.x >> 4) << 1);
    const int c0 = colBase + ((threadIdx.x & 15) << 1);
#pragma unroll
    for (int i = 0; i < 2; ++i) {
        int r = r0 + i;
        *(float2*)(Cb + (size_t)r * DD + c0) = (float2){acc[i][0], acc[i][1]};
    }
}

// comb: M_j = I + sum_{m=1..8} g_m^(j) cs^m K^m (j=1..32) -> bf16 MTb[j][c][k]
// + f32 W1..W5 = Kd^{32,64,96,128,160} + Zb0 = bf16(z0).
// g_m^(j) = sum_p C(j,p) C(j+m-p-1, m-p), exact in double (max ~3e15 < 2^53).
__global__ void __launch_bounds__(256)
comb_kernel(const float* __restrict__ Pw, const float* __restrict__ log_dt,
            const float* __restrict__ z0, unsigned short* __restrict__ MTb,
            float* __restrict__ W1, float* __restrict__ W2,
            float* __restrict__ W3, float* __restrict__ W4,
            float* __restrict__ W5, unsigned short* __restrict__ Zb0) {
    __shared__ float tle[8][32][33];
    __shared__ float gtab[36][8];
    const int tid = threadIdx.x;
    const int k0 = blockIdx.y << 5, c0 = blockIdx.x << 5;
    const float csf = 0.5f * expf(log_dt[0]);

    // fold prep: bf16(z0), 4 elems/thread
    {
        int b = ((blockIdx.y * 8 + blockIdx.x) * 256 + tid) * 4;
        uint2 w;
        w.x = pack2bf(z0[b], z0[b + 1]);
        w.y = pack2bf(z0[b + 2], z0[b + 3]);
        *(uint2*)(Zb0 + b) = w;
    }

    // coefficient rows: 0..31 -> j=1..32 ; 32..35 -> j=64,96,128,160
    if (tid < 36) {
        int j = (tid < 32) ? (tid + 1) : (32 * (tid - 30));  // 64,96,128,160
        double b[9], cq[9];
        b[0] = 1.0;
        cq[0] = 1.0;
#pragma unroll
        for (int p = 1; p <= 8; ++p) {
            b[p] = b[p - 1] * (double)(j - p + 1) / (double)p;   // C(j,p)
            cq[p] = cq[p - 1] * (double)(j + p - 1) / (double)p; // C(j+p-1,p)
        }
        double csm = (double)csf;
#pragma unroll
        for (int m = 1; m <= 8; ++m) {
            double s = 0.0;
#pragma unroll
            for (int p = 0; p <= 8; ++p)
                if (p <= m) s += b[p] * cq[m - p];
            gtab[tid][m - 1] = (float)(s * csm);
            csm *= (double)csf;
        }
    }

    const int ltx = tid & 31, lty = tid >> 5;
#pragma unroll
    for (int m = 0; m < 8; ++m)
#pragma unroll
        for (int it = 0; it < 4; ++it) {
            int k = lty + (it << 3);
            tle[m][ltx][k] =
                Pw[(size_t)m * MATF + (size_t)(k0 + k) * DD + c0 + ltx];
        }
    __syncthreads();

    const int c = tid >> 3;
    const int kb = (tid & 7) << 2;
    float em[8][4];
#pragma unroll
    for (int m = 0; m < 8; ++m)
#pragma unroll
        for (int u = 0; u < 4; ++u) em[m][u] = tle[m][c][kb + u];

    float diag[4];
#pragma unroll
    for (int u = 0; u < 4; ++u)
        diag[u] = ((k0 + kb + u) == (c0 + c)) ? 1.f : 0.f;

    float w32[4];
    for (int j = 1; j <= 32; ++j) {
        float val[4] = {diag[0], diag[1], diag[2], diag[3]};
        const float* gj = gtab[j - 1];
#pragma unroll
        for (int m = 0; m < 8; ++m)
#pragma unroll
            for (int u = 0; u < 4; ++u) val[u] = fmaf(gj[m], em[m][u], val[u]);
        uint2 w;
        w.x = pack2bf(val[0], val[1]);
        w.y = pack2bf(val[2], val[3]);
        *(uint2*)(MTb + (size_t)(j - 1) * MATF + (size_t)(c0 + c) * DD + k0 + kb) = w;
        if (j == 32) {
            w32[0] = val[0]; w32[1] = val[1]; w32[2] = val[2]; w32[3] = val[3];
        }
    }
    float wv[4][4];
#pragma unroll
    for (int q = 0; q < 4; ++q)
#pragma unroll
        for (int u = 0; u < 4; ++u) wv[q][u] = diag[u];
#pragma unroll
    for (int m = 0; m < 8; ++m)
#pragma unroll
        for (int q = 0; q < 4; ++q)
#pragma unroll
            for (int u = 0; u < 4; ++u)
                wv[q][u] = fmaf(gtab[32 + q][m], em[m][u], wv[q][u]);

    // five LDS-transpose passes -> coalesced f32 stores in [k][c] layout
    float* tw = &tle[0][0][0];
    const int wk = tid >> 3, wc = (tid & 7) << 2;
    float* Wd[5] = {W1, W2, W3, W4, W5};
    float* Ws[5] = {w32, wv[0], wv[1], wv[2], wv[3]};
#pragma unroll
    for (int p = 0; p < 5; ++p) {
        __syncthreads();
#pragma unroll
        for (int u = 0; u < 4; ++u) tw[(kb + u) * 33 + c] = Ws[p][u];
        __syncthreads();
        float4 v = {tw[wk * 33 + wc], tw[wk * 33 + wc + 1],
                    tw[wk * 33 + wc + 2], tw[wk * 33 + wc + 3]};
        *(float4*)(Wd[p] + (size_t)(k0 + wk) * DD + c0 + wc) = v;
    }
}

// 2-level checkpoint scan, contiguous operands.
// a: 0=z0, 1..15=Zf[a], 16+k=Wp[k]; b: Wp index; d: 1..15=Z_dst, 19=Wtab (W10).
// Wp = {W1,W2,W3,W4,W5,W10}.
// L0 (6): Z1..Z5 = z0@W1..5 ; W10 = W5@W5.
// L1 (10): Z6..Z10 = Z1..5@W5 ; Z11..Z15 = Z1..5@W10.
__global__ void __launch_bounds__(256)
scan2_kernel(const float* __restrict__ z0, float* __restrict__ Zf,
             const float* __restrict__ W1, const float* __restrict__ W2,
             const float* __restrict__ W3, const float* __restrict__ W4,
             const float* __restrict__ W5, float* __restrict__ Wtab,
             unsigned short* __restrict__ Zb, int level) {
    static const signed char JA[2][10] = {
        {0, 0, 0, 0, 0, 20, 0, 0, 0, 0},
        {1, 2, 3, 4, 5, 1, 2, 3, 4, 5}};
    static const signed char JB[2][10] = {
        {0, 1, 2, 3, 4, 4, 0, 0, 0, 0},
        {4, 4, 4, 4, 4, 5, 5, 5, 5, 5}};
    static const signed char JD[2][10] = {
        {1, 2, 3, 4, 5, 19, 0, 0, 0, 0},
        {6, 7, 8, 9, 10, 11, 12, 13, 14, 15}};
    const float* Wp[6] = {W1, W2, W3, W4, W5, Wtab};
    const int jz = blockIdx.z;
    const int a = JA[level][jz], b = JB[level][jz], d = JD[level][jz];

    const float* Asrc;
    if (a == 0) Asrc = z0;
    else if (a < 16) Asrc = Zf + (size_t)a * MATF;
    else Asrc = Wp[a - 16];

    float acc[2][2];
    const int rowBase = blockIdx.y << 5, colBase = blockIdx.x << 5;
    g32_core(Asrc, DD, Wp[b], DD, rowBase, colBase, acc);

    const int r0 = rowBase + ((threadIdx.x >> 4) << 1);
    const int c0 = colBase + ((threadIdx.x & 15) << 1);
    if (d < 16) {
        float* Zo32 = Zf + (size_t)d * MATF;
        unsigned short* Zo = Zb + (size_t)d * MATF;
#pragma unroll
        for (int ii = 0; ii < 2; ++ii) {
            int r = r0 + ii;
            float2 v = {acc[ii][0], acc[ii][1]};
            *(float2*)(Zo32 + (size_t)r * DD + c0) = v;
            *(unsigned*)(Zo + (size_t)r * DD + c0) = pack2bf(v.x, v.y);
        }
    } else {
        float* Cb = Wtab;
#pragma unroll
        for (int ii = 0; ii < 2; ++ii) {
            int r = r0 + ii;
            *(float2*)(Cb + (size_t)r * DD + c0) = (float2){acc[ii][0], acc[ii][1]};
        }
    }
}

// Batched bf16 MFMA fill (proven r8/r10/r13), all 512 timesteps, j-major.
__global__ void __launch_bounds__(256)
fill_kernel(const unsigned short* __restrict__ Zb,
            const unsigned short* __restrict__ MTb,
            float* __restrict__ out) {
    __shared__ __align__(16) char pool[32768];
    const int zz = blockIdx.z;
    const int i = zz & 15;
    const int j = (zz >> 4) + 1;
    const int t = i * 32 + j - 1;
    const unsigned short* Zt = Zb + (size_t)i * MATF;
    const unsigned short* MT = MTb + (size_t)(j - 1) * MATF;

    const int tid = threadIdx.x;
    const int lane = tid & 63, wid = tid >> 6;
    const int rowBase = blockIdx.y * 128, colBase = blockIdx.x * 128;
    const int wr = (wid >> 1) * 64, wc = (wid & 1) * 64;

    int rowq[4], skq[4], ldsb[4];
#pragma unroll
    for (int q = 0; q < 4; ++q) {
        int c = q * 256 + wid * 64 + lane;
        int row = c >> 3;
        rowq[q] = row;
        skq[q] = ((c ^ (row & 7)) & 7) << 3;
        ldsb[q] = (q * 256 + wid * 64) << 4;
    }

    f32x4 acc[4][4];
#pragma unroll
    for (int a = 0; a < 4; ++a)
#pragma unroll
        for (int b = 0; b < 4; ++b) acc[a][b] = (f32x4){0.f, 0.f, 0.f, 0.f};

    auto stage = [&](int k0) {
#pragma unroll
        for (int q = 0; q < 4; ++q) {
            GLD16(Zt + (size_t)(rowBase + rowq[q]) * DD + k0 + skq[q], pool + ldsb[q]);
            GLD16(MT + (size_t)(colBase + rowq[q]) * DD + k0 + skq[q],
                  pool + 16384 + ldsb[q]);
        }
    };

    stage(0);
    for (int r = 0; r < 4; ++r) {
        __syncthreads();
        const char* asb = pool;
        const char* bsb = pool + 16384;
#pragma unroll
        for (int ks = 0; ks < 2; ++ks) {
            bf16x8 af[4], bg[4];
            const int kk = ks * 32 + (lane >> 4) * 8;
#pragma unroll
            for (int f = 0; f < 4; ++f) {
                int rr = wr + f * 16 + (lane & 15);
                af[f] = *(const bf16x8*)(asb + ((rr * 128 + kk * 2) ^ ((rr & 7) << 4)));
                int cc = wc + f * 16 + (lane & 15);
                bg[f] = *(const bf16x8*)(bsb + ((cc * 128 + kk * 2) ^ ((cc & 7) << 4)));
            }
#pragma unroll
            for (int fr = 0; fr < 4; ++fr)
#pragma unroll
                for (int fc = 0; fc < 4; ++fc)
                    acc[fr][fc] = __builtin_amdgcn_mfma_f32_16x16x32_bf16(
                        af[fr], bg[fc], acc[fr][fc], 0, 0, 0);
        }
        __syncthreads();
        if (r < 3) stage((r + 1) * 64);
    }

    float* Cs = (float*)pool;
    float* C = out + (size_t)t * DD;
#pragma unroll
    for (int hp = 0; hp < 2; ++hp) {
        __syncthreads();
        if (wr == hp * 64) {
#pragma unroll
            for (int fr = 0; fr < 4; ++fr) {
#pragma unroll
                for (int fc = 0; fc < 4; ++fc) {
                    int ccol = wc + fc * 16 + (lane & 15);
#pragma unroll
                    for (int ii = 0; ii < 4; ++ii) {
                        int lr = fr * 16 + ((lane >> 4) << 2) + ii;
                        int csw = ccol ^ (((lr >> 2) & 1) << 4);
                        Cs[lr * 128 + csw] = acc[fr][fc][ii];
                    }
                }
            }
        }
        __syncthreads();
#pragma unroll
        for (int it = 0; it < 8; ++it) {
            int chunk = it * 256 + tid;
            int row = chunk >> 5;
            int c4 = (chunk & 31) << 2;
            int csw = c4 ^ (((row >> 2) & 1) << 4);
            float4 v = *(const float4*)(Cs + row * 128 + csw);
            *(float4*)(C + (size_t)(rowBase + hp * 64 + row) * LDT + colBase + c4) = v;
        }
    }
}

// ---------------- fallback (tiny ws): proven g32 chain ----------------------
__global__ void prep_kernel(const float* __restrict__ K,
                            const float* __restrict__ log_dt,
                            float* __restrict__ A) {
    int idx = blockIdx.x * blockDim.x + threadIdx.x;
    A[idx] = 0.5f * expf(log_dt[0]) * K[idx];
}

template <int EPI>
__global__ void __launch_bounds__(256)
g32_kernel(const float* A, const float* B, float* C, const float* E, float* C2,
           int lda, int ldb, int ldc, long long sA, long long sB, long long sC) {
    float acc[2][2];
    const int rowBase = blockIdx.y << 5, colBase = blockIdx.x << 5;
    g32_core(A + blockIdx.z * sA, lda, B + blockIdx.z * sB, ldb, rowBase, colBase, acc);
    float* Cb = C + blockIdx.z * sC;
    const int r0 = rowBase + ((threadIdx.x >> 4) << 1);
    const int c0 = colBase + ((threadIdx.x & 15) << 1);
#pragma unroll
    for (int i = 0; i < 2; ++i) {
        int r = r0 + i;
        float2 v;
        if (EPI == 2) {
            float e0 = E[(size_t)r * DD + c0], e1 = E[(size_t)r * DD + c0 + 1];
            v.x = acc[i][0] + 2.f * e0 + (r == c0 ? 1.f : 0.f);
            v.y = acc[i][1] + 2.f * e1 + (r == c0 + 1 ? 1.f : 0.f);
        } else {
            v.x = acc[i][0];
            v.y = acc[i][1];
        }
        *(float2*)(Cb + (size_t)r * ldc + c0) = v;
        if (EPI == 1) {
            float e0 = E[(size_t)r * DD + c0], e1 = E[(size_t)r * DD + c0 + 1];
            float2 w;
            w.x = 2.f * acc[i][0] + 2.f * e0 + (r == c0 ? 2.f : 0.f);
            w.y = 2.f * acc[i][1] + 2.f * e1 + (r == c0 + 1 ? 2.f : 0.f);
            *(float2*)(C2 + (size_t)r * DD + c0) = w;
        }
    }
}

// ---------------- launch ----------------------------------------------------
extern "C" void kernel_launch(void* const* d_in, const int* in_sizes, int n_in,
                              void* d_out, int out_size, void* d_ws, size_t ws_size,
                              hipStream_t stream) {
    const float* z0 = (const float*)d_in[0];
    const float* Kmat = (const float*)d_in[1];
    const float* log_dt = (const float*)d_in[2];
    float* out = (float*)d_out;

    dim3 blk(256);

    // ws: Pw[8] (K..K^8) | W1..W5 | Wtab[1] (W10) | Zf[16] f32
    //     | MTb[32] | Zb[16] bf16
    float* Pw = (float*)d_ws;
    float* W1 = Pw + (size_t)8 * MATF;
    float* W2 = W1 + MATF;
    float* W3 = W2 + MATF;
    float* W4 = W3 + MATF;
    float* W5 = W4 + MATF;
    float* Wtab = W5 + MATF;
    float* Zf = Wtab + MATF;
    unsigned short* MTb = (unsigned short*)(Zf + (size_t)16 * MATF);
    unsigned short* Zb = MTb + (size_t)32 * MATF;
    const size_t need = (size_t)30 * MATF * 4 + (size_t)48 * MATF * 2;

    if (ws_size >= need) {
        dim3 g(8, 8, 1);
        // K-powers: K^2 ; {K^3, K^4} ; {K^5..K^8}
        p1_kernel<<<g, blk, 0, stream>>>(Kmat, Pw);
        gpow_kernel<<<dim3(8, 8, 2), blk, 0, stream>>>(
            Pw, Pw + MATF, Pw + 2 * (size_t)MATF, MATF, 0, MATF);
        gpow4_kernel<<<dim3(8, 8, 4), blk, 0, stream>>>(Pw);

        // All 32 M-tables (bf16-T) + W1..W5 f32 + bf16(z0), one launch
        comb_kernel<<<g, blk, 0, stream>>>(Pw, log_dt, z0, MTb, W1, W2, W3, W4,
                                           W5, Zb);

        // checkpoint scan: 2 batched levels
        scan2_kernel<<<dim3(8, 8, 6), blk, 0, stream>>>(z0, Zf, W1, W2, W3, W4,
                                                        W5, Wtab, Zb, 0);
        scan2_kernel<<<dim3(8, 8, 10), blk, 0, stream>>>(z0, Zf, W1, W2, W3, W4,
                                                         W5, Wtab, Zb, 1);

        // ALL 512 timesteps, j-major order
        fill_kernel<<<dim3(2, 2, 512), blk, 0, stream>>>(Zb, MTb, out);
        return;
    }

    // Minimal fallback (tiny ws): Kd then 512 chained GEMMs (f32, proven core).
    float* A = (float*)d_ws;
    float* A2f = A + MATF;
    float* Bopf = A2f + MATF;
    float* Kd = Bopf + MATF;
    prep_kernel<<<MATF / 256, blk, 0, stream>>>(Kmat, log_dt, A);
    dim3 g(8, 8, 1);
    g32_kernel<1><<<g, blk, 0, stream>>>(A, A, A2f, A, Bopf, DD, DD, DD, 0, 0, 0);
    g32_kernel<2><<<g, blk, 0, stream>>>(A2f, Bopf, Kd, A, (float*)0, DD, DD, DD, 0, 0, 0);
    for (int t = 0; t < TT; ++t) {
        const float* Ain = (t == 0) ? z0 : out + (size_t)(t - 1) * DD;
        int lda = (t == 0) ? DD : (int)LDT;
        g32_kernel<0><<<g, blk, 0, stream>>>(Ain, Kd, out + (size_t)t * DD,
                                             (const float*)0, (float*)0,
                                             lda, DD, (int)LDT, 0, 0, 0);
    }
}